// Round 5
// baseline (75.307 us; speedup 1.0000x reference)
//
#include <hip/hip_runtime.h>

#define NQ 12
#define NL 4
#define DIM 4096
#define BLOCK 1024
#define PER_T 4           // amplitudes per thread, bits 6..7 of index
#define BATCH 256

// Index layout: j = lane | (k<<6) | (wv<<8)
//   bits 0..5  = lane (64)  -> qubits 6..11 (DPP / permlane-swap gates, no DS)
//   bits 6..7  = reg k (4)  -> qubits 4..5  (register gates)
//   bits 8..11 = wave (16)  -> qubits 0..3  (two 4-point LDS stages + CX perm)
// Qubit q lives at bit position 11-q.

__device__ __forceinline__ float2 cmul(float2 a, float2 b) {
    return make_float2(a.x * b.x - a.y * b.y, a.x * b.y + a.y * b.x);
}

// ---- VALU lane exchanges (no DS traffic) ----------------------------------
// quad_perm xor1 = 0xB1, xor2 = 0x4E, xor3 = 0x1B; row_ror:8 = xor8 = 0x128;
// row_half_mirror = xor7 = 0x141.  xor4 = xor7 then xor3.
template <int CTRL>
__device__ __forceinline__ float dppx(float v) {
    int i = __builtin_bit_cast(int, v);
    int r = __builtin_amdgcn_update_dpp(0, i, CTRL, 0xF, 0xF, true);
    return __builtin_bit_cast(float, r);
}

// own + partner(lane^16) / (lane^32), orientation-independent:
// with both operands equal, the two swap outputs hold the two half-sets,
// so their lane-wise sum is own+partner under either operand orientation.
__device__ __forceinline__ float swap_sum16(float v) {
    float a = v, b = v;
    asm volatile("" : "+v"(b));   // keep b in its own register
    asm volatile("v_permlane16_swap_b32 %0, %1" : "+v"(a), "+v"(b));
    return a + b;
}
__device__ __forceinline__ float swap_sum32(float v) {
    float a = v, b = v;
    asm volatile("" : "+v"(b));
    asm volatile("v_permlane32_swap_b32 %0, %1" : "+v"(a), "+v"(b));
    return a + b;
}

// gate via direct partner value (DPP paths)
template <int MSK>
__device__ __forceinline__ void gate_partner(float2* psi, float px, float py, int k,
                                             float c, float se, float zr, float zie) {
    float nr = c * psi[k].x + se * px;
    float ni = c * psi[k].y + se * py;
    psi[k].x = nr * zr - ni * zie;
    psi[k].y = ni * zr + nr * zie;
}

template <int MSK, int CTRL>
__device__ __forceinline__ void gate_dpp(float2* psi, int lane,
                                         float c, float s, float zr, float zi) {
    const float se  = (lane & MSK) ? s  : -s;
    const float zie = (lane & MSK) ? zi : -zi;
#pragma unroll
    for (int k = 0; k < PER_T; ++k)
        gate_partner<MSK>(psi, dppx<CTRL>(psi[k].x), dppx<CTRL>(psi[k].y),
                          k, c, se, zr, zie);
}

// xor4 via two chained DPP movs
__device__ __forceinline__ void gate_dpp4(float2* psi, int lane,
                                          float c, float s, float zr, float zi) {
    const float se  = (lane & 4) ? s  : -s;
    const float zie = (lane & 4) ? zi : -zi;
#pragma unroll
    for (int k = 0; k < PER_T; ++k)
        gate_partner<4>(psi, dppx<0x1B>(dppx<0x141>(psi[k].x)),
                            dppx<0x1B>(dppx<0x141>(psi[k].y)),
                        k, c, se, zr, zie);
}

// xor16/xor32 via permlane swap; uses u = own+partner:
// c*own + se*(u-own) = (c-se)*own + se*u
template <bool IS32>
__device__ __forceinline__ void gate_swap(float2* psi, int lane,
                                          float c, float s, float zr, float zi) {
    const int msk = IS32 ? 32 : 16;
    const float se  = (lane & msk) ? s  : -s;
    const float cm  = c - se;
    const float zie = (lane & msk) ? zi : -zi;
#pragma unroll
    for (int k = 0; k < PER_T; ++k) {
        float ux = IS32 ? swap_sum32(psi[k].x) : swap_sum16(psi[k].x);
        float uy = IS32 ? swap_sum32(psi[k].y) : swap_sum16(psi[k].y);
        float nr = cm * psi[k].x + se * ux;
        float ni = cm * psi[k].y + se * uy;
        psi[k].x = nr * zr - ni * zie;
        psi[k].y = ni * zr + nr * zie;
    }
}

__global__ __launch_bounds__(BLOCK, 4) void qcp_kernel(
    const float* __restrict__ x,      // (BATCH, NQ)
    const float* __restrict__ w,      // (NL, NQ, 2) flat: [ry, rz] -> 96
    float* __restrict__ out)          // (BATCH,)
{
    __shared__ float2 sA[DIM];
    __shared__ float2 sB[DIM];
    __shared__ float2 trig[NL * NQ * 2];   // (cos, sin) of 0.5*w[idx]
    __shared__ float rbuf[16];

    const int b    = blockIdx.x;
    const int t    = threadIdx.x;
    const int lane = t & 63;
    const int wv   = t >> 6;               // 0..15

    if (t < NL * NQ * 2) {
        float sn, cs;
        sincosf(0.5f * w[t], &sn, &cs);
        trig[t] = make_float2(cs, sn);
    }

    float xr[NQ];
#pragma unroll
    for (int q = 0; q < NQ; ++q) xr[q] = x[b * NQ + q];

    // Data-encoding phasors (identical each layer).
    float2 eph[PER_T];
#pragma unroll
    for (int k = 0; k < PER_T; ++k) {
        int j = lane | (k << 6) | (wv << 8);
        float ang = 0.0f;
#pragma unroll
        for (int q = 0; q < NQ; ++q)
            ang += ((j >> (NQ - 1 - q)) & 1) ? 0.5f * xr[q] : -0.5f * xr[q];
        sincosf(ang, &eph[k].y, &eph[k].x);
    }

    float2 psi[PER_T];
#pragma unroll
    for (int k = 0; k < PER_T; ++k) psi[k] = make_float2(0.015625f, 0.0f);

    __syncthreads();   // trig ready

    for (int l = 0; l < NL; ++l) {
        // ---- 1) diagonal data-encoding phase -------------------------------
#pragma unroll
        for (int k = 0; k < PER_T; ++k) psi[k] = cmul(psi[k], eph[k]);

        // ---- 2) register-bit gates: qubits 4..5 ----------------------------
#pragma unroll
        for (int q = 4; q <= 5; ++q) {
            const int kb = 5 - q;
            float2 tr = trig[(l * NQ + q) * 2 + 0];
            float2 tz = trig[(l * NQ + q) * 2 + 1];
            float c = tr.x, s = tr.y, zr = tz.x, zi = tz.y;
#pragma unroll
            for (int m = 0; m < PER_T / 2; ++m) {
                int k0 = ((m >> kb) << (kb + 1)) | (m & ((1 << kb) - 1));
                int k1 = k0 | (1 << kb);
                float2 a0 = psi[k0], a1 = psi[k1];
                float n0r = c * a0.x - s * a1.x;
                float n0i = c * a0.y - s * a1.y;
                float n1r = s * a0.x + c * a1.x;
                float n1i = s * a0.y + c * a1.y;
                psi[k0] = make_float2(n0r * zr + n0i * zi, n0i * zr - n0r * zi);
                psi[k1] = make_float2(n1r * zr - n1i * zi, n1i * zr + n1r * zi);
            }
        }

        // ---- 3) lane-bit gates: qubits 6..11, all on VALU ------------------
        {
            const float2* tg = &trig[l * NQ * 2];
            gate_swap<true >(psi, lane, tg[12].x, tg[12].y, tg[13].x, tg[13].y); // q6  xor32
            gate_swap<false>(psi, lane, tg[14].x, tg[14].y, tg[15].x, tg[15].y); // q7  xor16
            gate_dpp<8, 0x128>(psi, lane, tg[16].x, tg[16].y, tg[17].x, tg[17].y); // q8
            gate_dpp4(psi, lane, tg[18].x, tg[18].y, tg[19].x, tg[19].y);          // q9
            gate_dpp<2, 0x4E>(psi, lane, tg[20].x, tg[20].y, tg[21].x, tg[21].y);  // q10
            gate_dpp<1, 0xB1>(psi, lane, tg[22].x, tg[22].y, tg[23].x, tg[23].y);  // q11
        }

        // ---- 4) wave-bit gates (qubits 0..3) + CX perm, two 4-point stages -
        float2 E0[2], E1[2], E2[2], E3[2];
        {
            const int r0 = (wv >> 3) & 1;                 // g bit11
            const int r1 = ((wv >> 2) ^ (wv >> 3)) & 1;   // g bit10
            const int r2 = (wv >> 1) & 1;                 // j bit9
            const int r3 = wv & 1;                        // j bit8
            const int rr[4] = {r0, r1, r2, r3};
            float2* EE[4] = {E0, E1, E2, E3};
#pragma unroll
            for (int q = 0; q < 4; ++q) {
                float2 tr = trig[(l * NQ + q) * 2 + 0];
                float2 tz = trig[(l * NQ + q) * 2 + 1];
                int r = rr[q];
                float e0 = r ? tr.y : tr.x;
                float e1 = r ? tr.x : -tr.y;
                float2 ph = make_float2(tz.x, r ? tz.y : -tz.y);
                EE[q][0] = make_float2(e0 * ph.x, e0 * ph.y);
                EE[q][1] = make_float2(e1 * ph.x, e1 * ph.y);
            }
        }
        float2 cA[4], cB[4];
#pragma unroll
        for (int c2 = 0; c2 < 4; ++c2) {
            cA[c2] = cmul(E2[c2 >> 1], E3[c2 & 1]);   // addr bits (9,8) = c2
            cB[c2] = cmul(E0[c2 >> 1], E1[c2 & 1]);   // addr bits (11,10) = c2
        }

        // stage the state
#pragma unroll
        for (int k = 0; k < PER_T; ++k) {
            int j = lane | (k << 6) | (wv << 8);
            sA[j] = psi[k];
        }
        __syncthreads();

        // stage A: gather over bits 9,8
#pragma unroll
        for (int k = 0; k < PER_T; ++k) {
            int base = lane | (k << 6) | ((wv >> 2) << 10);
            float2 r = make_float2(0.0f, 0.0f);
#pragma unroll
            for (int c = 0; c < 4; ++c) {
                float2 v = sA[base | (c << 8)];
                r.x += cA[c].x * v.x - cA[c].y * v.y;
                r.y += cA[c].x * v.y + cA[c].y * v.x;
            }
            sB[lane | (k << 6) | (wv << 8)] = r;
        }
        __syncthreads();

        // stage B: gather over bits 11,10 at Gray-permuted base (CX ladder)
        // NOTE: no trailing barrier — next layer's sA writes are ordered by
        // the barrier above (all sA reads precede it in program order).
#pragma unroll
        for (int k = 0; k < PER_T; ++k) {
            int j = lane | (k << 6) | (wv << 8);
            int g = j ^ (j >> 1);
            int base = g & 0x3FF;
            float2 r = make_float2(0.0f, 0.0f);
#pragma unroll
            for (int c = 0; c < 4; ++c) {
                float2 v = sB[base | (c << 10)];
                r.x += cB[c].x * v.x - cB[c].y * v.y;
                r.y += cB[c].x * v.y + cB[c].y * v.x;
            }
            psi[k] = r;
        }
    }

    // ---- <Z(0)>: qubit 0 = bit 11 = wave bit 3 ----------------------------
    float acc = 0.0f;
#pragma unroll
    for (int k = 0; k < PER_T; ++k)
        acc += psi[k].x * psi[k].x + psi[k].y * psi[k].y;
    if (wv >= 8) acc = -acc;
#pragma unroll
    for (int off = 32; off > 0; off >>= 1)
        acc += __shfl_down(acc, off, 64);
    if (lane == 0) rbuf[wv] = acc;
    __syncthreads();
    if (t == 0) {
        float tot = 0.0f;
#pragma unroll
        for (int i = 0; i < 16; ++i) tot += rbuf[i];
        out[b] = tot;
    }
}

extern "C" void kernel_launch(void* const* d_in, const int* in_sizes, int n_in,
                              void* d_out, int out_size, void* d_ws, size_t ws_size,
                              hipStream_t stream) {
    const float* x = (const float*)d_in[0];   // (256, 12)
    const float* w = (const float*)d_in[1];   // (96,)
    float* out = (float*)d_out;               // (256, 1)
    qcp_kernel<<<BATCH, BLOCK, 0, stream>>>(x, w, out);
}

// Round 7
// 75.284 us; speedup vs baseline: 1.0003x; 1.0003x over previous
//
#include <hip/hip_runtime.h>

#define NQ 12
#define NL 4
#define DIM 4096
#define BLOCK 1024
#define PER_T 4           // amplitudes per thread, bits 6..7 of index
#define BATCH 256

// Index layout: j = lane | (k<<6) | (wv<<8)
//   bits 0..5  = lane (64)  -> qubits 6..11 (shfl/DPP RY gates)
//   bits 6..7  = reg k (4)  -> qubits 4..5  (register RY gates)
//   bits 8..11 = wave (16)  -> qubits 0..3  (two 4-point LDS stages + CX perm)
// Qubit q lives at bit position 11-q.
// Layer algebra: RY(q) and RZ(q') commute for q != q', so the reference's
// per-qubit RY,RZ interleave == (all RYs) then (all RZs). The 8 lane/reg RZs
// are fused into ONE per-amplitude diagonal phasor; wave-qubit RZs stay in
// the gather coefficients. RZ(q) is applied after RY(q) in all paths.

__device__ __forceinline__ float2 cmul(float2 a, float2 b) {
    return make_float2(a.x * b.x - a.y * b.y, a.x * b.y + a.y * b.x);
}

// ---- lane exchanges -------------------------------------------------------
// DPP (VALU pipe): quad_perm xor1 = 0xB1, xor2 = 0x4E; row_ror:8 = xor8 = 0x128.
// Masks 4/16/32 use __shfl_xor (DS pipe) — proven correct (R3), and R3/R4 A/B
// showed the DS pipe is not binding at this operating point.
template <int CTRL>
__device__ __forceinline__ float dppx(float v) {
    int i = __builtin_bit_cast(int, v);
    int r = __builtin_amdgcn_update_dpp(0, i, CTRL, 0xF, 0xF, true);
    return __builtin_bit_cast(float, r);
}

// RY-only gate: x' = c*x + se*partner_x
template <int MSK, int CTRL>
__device__ __forceinline__ void ry_dpp(float2* psi, int lane, float c, float s) {
    const float se = (lane & MSK) ? s : -s;
#pragma unroll
    for (int k = 0; k < PER_T; ++k) {
        float px = dppx<CTRL>(psi[k].x);
        float py = dppx<CTRL>(psi[k].y);
        psi[k].x = c * psi[k].x + se * px;
        psi[k].y = c * psi[k].y + se * py;
    }
}

template <int MSK>
__device__ __forceinline__ void ry_shfl(float2* psi, int lane, float c, float s) {
    const float se = (lane & MSK) ? s : -s;
#pragma unroll
    for (int k = 0; k < PER_T; ++k) {
        float px = __shfl_xor(psi[k].x, MSK, 64);
        float py = __shfl_xor(psi[k].y, MSK, 64);
        psi[k].x = c * psi[k].x + se * px;
        psi[k].y = c * psi[k].y + se * py;
    }
}

__global__ __launch_bounds__(BLOCK, 4) void qcp_kernel(
    const float* __restrict__ x,      // (BATCH, NQ)
    const float* __restrict__ w,      // (NL, NQ, 2) flat: [ry, rz] -> 96
    float* __restrict__ out)          // (BATCH,)
{
    __shared__ float2 sA[DIM];
    __shared__ float2 sB[DIM];
    __shared__ float2 trig[NL * NQ * 2];   // (cos, sin) of 0.5*w[idx]
    __shared__ float  zhalf[NL * NQ];      // 0.5 * rz weight
    __shared__ float  rbuf[16];

    const int b    = blockIdx.x;
    const int t    = threadIdx.x;
    const int lane = t & 63;
    const int wv   = t >> 6;               // 0..15

    if (t < NL * NQ * 2) {
        float sn, cs;
        sincosf(0.5f * w[t], &sn, &cs);
        trig[t] = make_float2(cs, sn);
    }
    if (t < NL * NQ) zhalf[t] = 0.5f * w[2 * t + 1];

    float xr[NQ];
#pragma unroll
    for (int q = 0; q < NQ; ++q) xr[q] = x[b * NQ + q];

    // Data-encoding phasors (identical each layer).
    float2 eph[PER_T];
#pragma unroll
    for (int k = 0; k < PER_T; ++k) {
        int j = lane | (k << 6) | (wv << 8);
        float ang = 0.0f;
#pragma unroll
        for (int q = 0; q < NQ; ++q)
            ang += ((j >> (NQ - 1 - q)) & 1) ? 0.5f * xr[q] : -0.5f * xr[q];
        sincosf(ang, &eph[k].y, &eph[k].x);
    }

    float2 psi[PER_T];
#pragma unroll
    for (int k = 0; k < PER_T; ++k) psi[k] = make_float2(0.015625f, 0.0f);

    __syncthreads();   // trig/zhalf ready

    for (int l = 0; l < NL; ++l) {
        // ---- 0) batched layer-coefficient load into registers --------------
        float2 tRY[8];      // RY (c,s) for q=4..11
        float2 tE[4][2];    // q=0..3: RY(c,s), RZ(c,s)
        float  zh[8];       // 0.5*rz for q=4..11
#pragma unroll
        for (int q = 4; q <= 11; ++q) tRY[q - 4] = trig[(l * NQ + q) * 2];
#pragma unroll
        for (int q = 0; q < 4; ++q) {
            tE[q][0] = trig[(l * NQ + q) * 2 + 0];
            tE[q][1] = trig[(l * NQ + q) * 2 + 1];
        }
#pragma unroll
        for (int q = 4; q <= 11; ++q) zh[q - 4] = zhalf[l * NQ + q];

        // ---- 1) diagonal data-encoding phase -------------------------------
#pragma unroll
        for (int k = 0; k < PER_T; ++k) psi[k] = cmul(psi[k], eph[k]);

        // ---- 2) register-bit RY gates: qubits 4..5 -------------------------
#pragma unroll
        for (int q = 4; q <= 5; ++q) {
            const int kb = 5 - q;
            float c = tRY[q - 4].x, s = tRY[q - 4].y;
#pragma unroll
            for (int m = 0; m < PER_T / 2; ++m) {
                int k0 = ((m >> kb) << (kb + 1)) | (m & ((1 << kb) - 1));
                int k1 = k0 | (1 << kb);
                float2 a0 = psi[k0], a1 = psi[k1];
                psi[k0] = make_float2(c * a0.x - s * a1.x, c * a0.y - s * a1.y);
                psi[k1] = make_float2(s * a0.x + c * a1.x, s * a0.y + c * a1.y);
            }
        }

        // ---- 3) lane-bit RY gates: qubits 6..11 ----------------------------
        ry_shfl<32>(psi, lane, tRY[2].x, tRY[2].y);      // q6  xor32
        ry_shfl<16>(psi, lane, tRY[3].x, tRY[3].y);      // q7  xor16
        ry_dpp<8, 0x128>(psi, lane, tRY[4].x, tRY[4].y); // q8  xor8
        ry_shfl<4>(psi, lane, tRY[5].x, tRY[5].y);       // q9  xor4
        ry_dpp<2, 0x4E>(psi, lane, tRY[6].x, tRY[6].y);  // q10 xor2
        ry_dpp<1, 0xB1>(psi, lane, tRY[7].x, tRY[7].y);  // q11 xor1

        // ---- 4) fused RZ diagonal for qubits 4..11 -------------------------
        // angle(j) = sum_q (bit_{11-q}(j) ? +z_q/2 : -z_q/2)
        // lane bit p -> qubit 11-p -> zh[7-p]; k bit0 -> zh[1], k bit1 -> zh[0]
        float s_lane = 0.0f;
#pragma unroll
        for (int p = 0; p < 6; ++p)
            s_lane += ((lane >> p) & 1) ? zh[7 - p] : -zh[7 - p];
#pragma unroll
        for (int k = 0; k < PER_T; ++k) {
            float ang = s_lane + ((k & 1) ? zh[1] : -zh[1])
                               + ((k & 2) ? zh[0] : -zh[0]);
            float2 ph;
            sincosf(ang, &ph.y, &ph.x);
            psi[k] = cmul(psi[k], ph);
        }

        // ---- 5) wave-bit gates (qubits 0..3, RY+RZ) + CX perm, 2 stages ----
        float2 E0[2], E1[2], E2[2], E3[2];
        {
            const int r0 = (wv >> 3) & 1;                 // g bit11
            const int r1 = ((wv >> 2) ^ (wv >> 3)) & 1;   // g bit10
            const int r2 = (wv >> 1) & 1;                 // j bit9
            const int r3 = wv & 1;                        // j bit8
            const int rr[4] = {r0, r1, r2, r3};
            float2* EE[4] = {E0, E1, E2, E3};
#pragma unroll
            for (int q = 0; q < 4; ++q) {
                float2 tr = tE[q][0];
                float2 tz = tE[q][1];
                int r = rr[q];
                float e0 = r ? tr.y : tr.x;
                float e1 = r ? tr.x : -tr.y;
                float2 ph = make_float2(tz.x, r ? tz.y : -tz.y);
                EE[q][0] = make_float2(e0 * ph.x, e0 * ph.y);
                EE[q][1] = make_float2(e1 * ph.x, e1 * ph.y);
            }
        }
        float2 cA[4], cB[4];
#pragma unroll
        for (int c2 = 0; c2 < 4; ++c2) {
            cA[c2] = cmul(E2[c2 >> 1], E3[c2 & 1]);   // addr bits (9,8)
            cB[c2] = cmul(E0[c2 >> 1], E1[c2 & 1]);   // addr bits (11,10)
        }

#pragma unroll
        for (int k = 0; k < PER_T; ++k) {
            int j = lane | (k << 6) | (wv << 8);
            sA[j] = psi[k];
        }
        __syncthreads();

        // stage A: gather over bits 9,8
#pragma unroll
        for (int k = 0; k < PER_T; ++k) {
            int base = lane | (k << 6) | ((wv >> 2) << 10);
            float2 r = make_float2(0.0f, 0.0f);
#pragma unroll
            for (int c = 0; c < 4; ++c) {
                float2 v = sA[base | (c << 8)];
                r.x += cA[c].x * v.x - cA[c].y * v.y;
                r.y += cA[c].x * v.y + cA[c].y * v.x;
            }
            sB[lane | (k << 6) | (wv << 8)] = r;
        }
        __syncthreads();

        // stage B: gather over bits 11,10 at Gray-permuted base (CX ladder).
        // No trailing barrier: all sB reads precede the next layer's stage-A
        // sB writes, which sit behind that layer's barrier1.
#pragma unroll
        for (int k = 0; k < PER_T; ++k) {
            int j = lane | (k << 6) | (wv << 8);
            int g = j ^ (j >> 1);
            int base = g & 0x3FF;
            float2 r = make_float2(0.0f, 0.0f);
#pragma unroll
            for (int c = 0; c < 4; ++c) {
                float2 v = sB[base | (c << 10)];
                r.x += cB[c].x * v.x - cB[c].y * v.y;
                r.y += cB[c].x * v.y + cB[c].y * v.x;
            }
            psi[k] = r;
        }
    }

    // ---- <Z(0)>: qubit 0 = bit 11 = wave bit 3 ----------------------------
    float acc = 0.0f;
#pragma unroll
    for (int k = 0; k < PER_T; ++k)
        acc += psi[k].x * psi[k].x + psi[k].y * psi[k].y;
    if (wv >= 8) acc = -acc;
#pragma unroll
    for (int off = 32; off > 0; off >>= 1)
        acc += __shfl_down(acc, off, 64);
    if (lane == 0) rbuf[wv] = acc;
    __syncthreads();
    if (t == 0) {
        float tot = 0.0f;
#pragma unroll
        for (int i = 0; i < 16; ++i) tot += rbuf[i];
        out[b] = tot;
    }
}

extern "C" void kernel_launch(void* const* d_in, const int* in_sizes, int n_in,
                              void* d_out, int out_size, void* d_ws, size_t ws_size,
                              hipStream_t stream) {
    const float* x = (const float*)d_in[0];   // (256, 12)
    const float* w = (const float*)d_in[1];   // (96,)
    float* out = (float*)d_out;               // (256, 1)
    qcp_kernel<<<BATCH, BLOCK, 0, stream>>>(x, w, out);
}

// Round 8
// 74.530 us; speedup vs baseline: 1.0104x; 1.0101x over previous
//
#include <hip/hip_runtime.h>

#define NQ 12
#define NL 4
#define DIM 4096
#define BLOCK 1024
#define PER_T 4           // amplitudes per thread, bits 6..7 of index
#define BATCH 256

// Index layout: j = lane | (k<<6) | (wv<<8)
//   bits 0..5  = lane (64)  -> qubits 6..11 (shfl/DPP RY gates)
//   bits 6..7  = reg k (4)  -> qubits 4..5  (register RY gates)
//   bits 8..11 = wave (16)  -> qubits 0..3  (two 4-point LDS stages + CX perm)
// Qubit q lives at bit position 11-q.
// Layer algebra: RY(q) and RZ(q') commute for q != q', so the reference's
// per-qubit RY,RZ interleave == (all RYs) then (all RZs). The 8 lane/reg RZs
// fuse into ONE per-amplitude diagonal phasor; wave-qubit RZs stay in the
// gather coefficients. RZ(q) is applied after RY(q) in all paths.

__device__ __forceinline__ float2 cmul(float2 a, float2 b) {
    return make_float2(a.x * b.x - a.y * b.y, a.x * b.y + a.y * b.x);
}
__device__ __forceinline__ float2 cconj(float2 a) { return make_float2(a.x, -a.y); }

// HW sincos: v_sin/v_cos take revolutions; v_fract reduces. ~4 instrs total.
// |err| ~1e-6 vs threshold 1.37e-2.
__device__ __forceinline__ float2 fsincos(float ang) {   // returns (cos, sin)
    float r = ang * 0.15915494309189535f;                // rad -> rev
    r = r - floorf(r);
    return make_float2(__builtin_amdgcn_cosf(r), __builtin_amdgcn_sinf(r));
}

// ---- lane exchanges -------------------------------------------------------
// DPP (VALU pipe): quad_perm xor1 = 0xB1, xor2 = 0x4E; row_ror:8 = xor8 = 0x128.
// Masks 4/16/32 use __shfl_xor (DS pipe; proven correct, DS not binding here).
template <int CTRL>
__device__ __forceinline__ float dppx(float v) {
    int i = __builtin_bit_cast(int, v);
    int r = __builtin_amdgcn_update_dpp(0, i, CTRL, 0xF, 0xF, true);
    return __builtin_bit_cast(float, r);
}

template <int MSK, int CTRL>
__device__ __forceinline__ void ry_dpp(float2* psi, int lane, float c, float s) {
    const float se = (lane & MSK) ? s : -s;
#pragma unroll
    for (int k = 0; k < PER_T; ++k) {
        float px = dppx<CTRL>(psi[k].x);
        float py = dppx<CTRL>(psi[k].y);
        psi[k].x = c * psi[k].x + se * px;
        psi[k].y = c * psi[k].y + se * py;
    }
}

template <int MSK>
__device__ __forceinline__ void ry_shfl(float2* psi, int lane, float c, float s) {
    const float se = (lane & MSK) ? s : -s;
#pragma unroll
    for (int k = 0; k < PER_T; ++k) {
        float px = __shfl_xor(psi[k].x, MSK, 64);
        float py = __shfl_xor(psi[k].y, MSK, 64);
        psi[k].x = c * psi[k].x + se * px;
        psi[k].y = c * psi[k].y + se * py;
    }
}

__global__ __launch_bounds__(BLOCK, 4) void qcp_kernel(
    const float* __restrict__ x,      // (BATCH, NQ)
    const float* __restrict__ w,      // (NL, NQ, 2) flat: [ry, rz] -> 96
    float* __restrict__ out)          // (BATCH,)
{
    __shared__ float2 sA[DIM];
    __shared__ float2 sB[DIM];
    __shared__ float2 trig[NL * NQ * 2];   // (cos, sin) of 0.5*w[idx]
    __shared__ float  zhalf[NL * NQ];      // 0.5 * rz weight
    __shared__ float  rbuf[16];

    const int b    = blockIdx.x;
    const int t    = threadIdx.x;
    const int lane = t & 63;
    const int wv   = t >> 6;               // 0..15

    if (t < NL * NQ * 2) trig[t] = fsincos(0.5f * w[t]);
    if (t < NL * NQ) zhalf[t] = 0.5f * w[2 * t + 1];

    float xr[NQ];
#pragma unroll
    for (int q = 0; q < NQ; ++q) xr[q] = x[b * NQ + q];

    // Data-encoding phasors (identical each layer).
    float2 eph[PER_T];
#pragma unroll
    for (int k = 0; k < PER_T; ++k) {
        int j = lane | (k << 6) | (wv << 8);
        float ang = 0.0f;
#pragma unroll
        for (int q = 0; q < NQ; ++q)
            ang += ((j >> (NQ - 1 - q)) & 1) ? 0.5f * xr[q] : -0.5f * xr[q];
        eph[k] = fsincos(ang);                // (cos, sin)
    }

    float2 psi[PER_T];
#pragma unroll
    for (int k = 0; k < PER_T; ++k) psi[k] = make_float2(0.015625f, 0.0f);

    __syncthreads();   // trig/zhalf ready

    for (int l = 0; l < NL; ++l) {
        // ---- 0) batched layer-coefficient load into registers --------------
        float2 tRY[8];      // RY (c,s) for q=4..11
        float2 tE[4][2];    // q=0..3: RY(c,s), RZ(c,s)
        float  zh[6];       // 0.5*rz for q=6..11 (lane qubits)
        float2 z4, z5;      // e^{i*0.5*rz} for q=4, q=5 (reg qubits)
#pragma unroll
        for (int q = 4; q <= 11; ++q) tRY[q - 4] = trig[(l * NQ + q) * 2];
#pragma unroll
        for (int q = 0; q < 4; ++q) {
            tE[q][0] = trig[(l * NQ + q) * 2 + 0];
            tE[q][1] = trig[(l * NQ + q) * 2 + 1];
        }
        z4 = trig[(l * NQ + 4) * 2 + 1];
        z5 = trig[(l * NQ + 5) * 2 + 1];
#pragma unroll
        for (int q = 6; q <= 11; ++q) zh[q - 6] = zhalf[l * NQ + q];

        // ---- 1) diagonal data-encoding phase -------------------------------
#pragma unroll
        for (int k = 0; k < PER_T; ++k) psi[k] = cmul(psi[k], eph[k]);

        // ---- 2) register-bit RY gates: qubits 4..5 -------------------------
#pragma unroll
        for (int q = 4; q <= 5; ++q) {
            const int kb = 5 - q;
            float c = tRY[q - 4].x, s = tRY[q - 4].y;
#pragma unroll
            for (int m = 0; m < PER_T / 2; ++m) {
                int k0 = ((m >> kb) << (kb + 1)) | (m & ((1 << kb) - 1));
                int k1 = k0 | (1 << kb);
                float2 a0 = psi[k0], a1 = psi[k1];
                psi[k0] = make_float2(c * a0.x - s * a1.x, c * a0.y - s * a1.y);
                psi[k1] = make_float2(s * a0.x + c * a1.x, s * a0.y + c * a1.y);
            }
        }

        // ---- 3) lane-bit RY gates: qubits 6..11 ----------------------------
        ry_shfl<32>(psi, lane, tRY[2].x, tRY[2].y);      // q6  xor32
        ry_shfl<16>(psi, lane, tRY[3].x, tRY[3].y);      // q7  xor16
        ry_dpp<8, 0x128>(psi, lane, tRY[4].x, tRY[4].y); // q8  xor8
        ry_shfl<4>(psi, lane, tRY[5].x, tRY[5].y);       // q9  xor4
        ry_dpp<2, 0x4E>(psi, lane, tRY[6].x, tRY[6].y);  // q10 xor2
        ry_dpp<1, 0xB1>(psi, lane, tRY[7].x, tRY[7].y);  // q11 xor1

        // ---- 4) fused RZ diagonal for qubits 4..11 -------------------------
        // angle(j) = s_lane(lane bits; q6..11) + (k&1 ? +zh5 : -zh5)
        //                                      + (k&2 ? +zh4 : -zh4)
        // The k-dependent factors are e^{±i zh} = trig RZ pairs -> no sincos.
        float s_lane = 0.0f;
#pragma unroll
        for (int p = 0; p < 6; ++p)          // lane bit p -> qubit 11-p -> zh[5-p]
            s_lane += ((lane >> p) & 1) ? zh[5 - p] : -zh[5 - p];
        {
            float2 base = fsincos(s_lane);           // e^{i s_lane}
            float2 z45  = cmul(z4, z5);              // e^{i(zh4+zh5)}
            float2 zd   = cmul(z5, cconj(z4));       // e^{i(zh5-zh4)}
            float2 zc[4] = { cconj(z45), zd, cconj(zd), z45 };  // k = 0..3
#pragma unroll
            for (int k = 0; k < PER_T; ++k)
                psi[k] = cmul(psi[k], cmul(base, zc[k]));
        }

        // ---- 5) wave-bit gates (qubits 0..3, RY+RZ) + CX perm, 2 stages ----
        float2 E0[2], E1[2], E2[2], E3[2];
        {
            const int r0 = (wv >> 3) & 1;                 // g bit11
            const int r1 = ((wv >> 2) ^ (wv >> 3)) & 1;   // g bit10
            const int r2 = (wv >> 1) & 1;                 // j bit9
            const int r3 = wv & 1;                        // j bit8
            const int rr[4] = {r0, r1, r2, r3};
            float2* EE[4] = {E0, E1, E2, E3};
#pragma unroll
            for (int q = 0; q < 4; ++q) {
                float2 tr = tE[q][0];
                float2 tz = tE[q][1];
                int r = rr[q];
                float e0 = r ? tr.y : tr.x;
                float e1 = r ? tr.x : -tr.y;
                float2 ph = make_float2(tz.x, r ? tz.y : -tz.y);
                EE[q][0] = make_float2(e0 * ph.x, e0 * ph.y);
                EE[q][1] = make_float2(e1 * ph.x, e1 * ph.y);
            }
        }
        float2 cA[4], cB[4];
#pragma unroll
        for (int c2 = 0; c2 < 4; ++c2) {
            cA[c2] = cmul(E2[c2 >> 1], E3[c2 & 1]);   // addr bits (9,8)
            cB[c2] = cmul(E0[c2 >> 1], E1[c2 & 1]);   // addr bits (11,10)
        }

#pragma unroll
        for (int k = 0; k < PER_T; ++k) {
            int j = lane | (k << 6) | (wv << 8);
            sA[j] = psi[k];
        }
        __syncthreads();

        // stage A: gather over bits 9,8
#pragma unroll
        for (int k = 0; k < PER_T; ++k) {
            int base = lane | (k << 6) | ((wv >> 2) << 10);
            float2 r = make_float2(0.0f, 0.0f);
#pragma unroll
            for (int c = 0; c < 4; ++c) {
                float2 v = sA[base | (c << 8)];
                r.x += cA[c].x * v.x - cA[c].y * v.y;
                r.y += cA[c].x * v.y + cA[c].y * v.x;
            }
            sB[lane | (k << 6) | (wv << 8)] = r;
        }
        __syncthreads();

        // stage B: gather over bits 11,10 at Gray-permuted base (CX ladder).
        // No trailing barrier: all sB reads precede the next layer's stage-A
        // sB writes, which sit behind that layer's barrier.
#pragma unroll
        for (int k = 0; k < PER_T; ++k) {
            int j = lane | (k << 6) | (wv << 8);
            int g = j ^ (j >> 1);
            int base = g & 0x3FF;
            float2 r = make_float2(0.0f, 0.0f);
#pragma unroll
            for (int c = 0; c < 4; ++c) {
                float2 v = sB[base | (c << 10)];
                r.x += cB[c].x * v.x - cB[c].y * v.y;
                r.y += cB[c].x * v.y + cB[c].y * v.x;
            }
            psi[k] = r;
        }
    }

    // ---- <Z(0)>: qubit 0 = bit 11 = wave bit 3 ----------------------------
    float acc = 0.0f;
#pragma unroll
    for (int k = 0; k < PER_T; ++k)
        acc += psi[k].x * psi[k].x + psi[k].y * psi[k].y;
    if (wv >= 8) acc = -acc;
#pragma unroll
    for (int off = 32; off > 0; off >>= 1)
        acc += __shfl_down(acc, off, 64);
    if (lane == 0) rbuf[wv] = acc;
    __syncthreads();
    if (t == 0) {
        float tot = 0.0f;
#pragma unroll
        for (int i = 0; i < 16; ++i) tot += rbuf[i];
        out[b] = tot;
    }
}

extern "C" void kernel_launch(void* const* d_in, const int* in_sizes, int n_in,
                              void* d_out, int out_size, void* d_ws, size_t ws_size,
                              hipStream_t stream) {
    const float* x = (const float*)d_in[0];   // (256, 12)
    const float* w = (const float*)d_in[1];   // (96,)
    float* out = (float*)d_out;               // (256, 1)
    qcp_kernel<<<BATCH, BLOCK, 0, stream>>>(x, w, out);
}